// Round 9
// baseline (388.208 us; speedup 1.0000x reference)
//
#include <hip/hip_runtime.h>
#include <stdint.h>

#define BB 32
#define CC 256
#define HH 56
#define WW 56
#define TAPS 9
#define NCONV 3
#define BN_EPS 1e-5f

typedef int int4v  __attribute__((ext_vector_type(4)));
typedef int int16v __attribute__((ext_vector_type(16)));

// v_mfma_i32_32x32x32_i8: A 4 VGPR (16 i8), B 4 VGPR, C/D 16 VGPR.
#define MFMA_I8(accv, av, bv) \
    asm("v_mfma_i32_32x32x32_i8 %0, %1, %2, %0" : "+v"(accv) : "v"(av), "v"(bv))

// ---------------- workspace layout (bytes) ----------------
#define ACT8_BYTES   ((size_t)BB * HH * WW * CC)
#define WPACK_BYTES  ((size_t)NCONV * 8 * 4 * TAPS * 2 * 64 * 16)

// LDS act tile: ch-half planes, px stride 32B, XOR bank swizzle on bits 4-5.
#define L_PX   32
#define L_ROW  (58 * L_PX)        // 1856
#define L_CH   (4 * L_ROW)        // 7424
#define L_BUF  (2 * L_CH)         // 14848 per buffer
#define NSTU   (4 * 58 * 4)       // 928 16B staging units per tile
#define SWZ(c) ((((c) ^ ((c) >> 2)) & 3) << 4)
#define OT_STRIDE 73728           // 4 g * 18 units * 1024 B (wpack ot stride)

// act8[n][h][w][c] = sign(x + bias0) in i8. LDS transpose for coalescing.
__global__ __launch_bounds__(256) void pack_act8_kernel(
    const float* __restrict__ x, const float* __restrict__ bias0,
    int8_t* __restrict__ act8)
{
    __shared__ int8_t ldsT[56 * 260];
    const int tid = threadIdx.x;
    const int h = blockIdx.x % HH, n = blockIdx.x / HH;
    const int w = tid & 63;
    const int cq = tid >> 6;
    if (w < WW) {
        #pragma unroll 4
        for (int cc = 0; cc < 64; ++cc) {
            const int c = cc * 4 + cq;
            const float v = x[((size_t)(n * CC + c) * HH + h) * WW + w] + bias0[c];
            ldsT[w * 260 + c] = (v > 0.f) ? (int8_t)1 : ((v < 0.f) ? (int8_t)-1 : (int8_t)0);
        }
    }
    __syncthreads();
    uint32_t* o32 = (uint32_t*)(act8 + (size_t)(n * HH + h) * WW * CC);
    #pragma unroll
    for (int i = 0; i < 14; ++i) {
        const int flat = i * 1024 + tid * 4;
        const int ww = flat >> 8, c4 = flat & 255;
        o32[flat >> 2] = *(const uint32_t*)(ldsT + ww * 260 + c4);
    }
}

// per-output-channel scale = mean |w| (one wave per (j,o)); epack fused in.
__global__ __launch_bounds__(64) void pack_scales_kernel(
    const float* __restrict__ w0, const float* __restrict__ w1,
    const float* __restrict__ w2, float* __restrict__ scales,
    const float* __restrict__ gamma, const float* __restrict__ beta,
    const float* __restrict__ rmean, const float* __restrict__ rvar,
    const float* __restrict__ bias1, const float* __restrict__ prelu_a,
    const float* __restrict__ bias2, float* __restrict__ epack)
{
    const int j = blockIdx.x >> 8;
    const int o = blockIdx.x & 255;
    const float* wp = (j == 0) ? w0 : ((j == 1) ? w1 : w2);
    const int lane = threadIdx.x;
    const float* wo = wp + (size_t)o * CC * TAPS;
    float s = 0.f;
    for (int k = lane; k < CC * TAPS; k += 64) s += fabsf(wo[k]);
    #pragma unroll
    for (int d = 32; d > 0; d >>= 1) s += __shfl_xor(s, d);
    if (lane == 0) scales[j * CC + o] = s * (1.0f / (float)(CC * TAPS));
    if (j == 0 && lane == 0) {
        const float A = gamma[o] * rsqrtf(rvar[o] + BN_EPS);
        epack[o * 4 + 0] = A;
        epack[o * 4 + 1] = beta[o] - rmean[o] * A + bias1[o];
        epack[o * 4 + 2] = prelu_a[o];
        epack[o * 4 + 3] = bias2[o];
    }
}

// weight signs in exact A-fragment order (verified r5-r8).
__global__ __launch_bounds__(256) void pack_wpack_kernel(
    const float* __restrict__ w0, const float* __restrict__ w1,
    const float* __restrict__ w2, int8_t* __restrict__ wpack)
{
    const int j  = blockIdx.x >> 3;
    const int ot = blockIdx.x & 7;
    const float* wp = (j == 0) ? w0 : ((j == 1) ? w1 : w2);
    const int tid = threadIdx.x;
    #pragma unroll 1
    for (int it = 0; it < 18; ++it) {
        const int e = it * 256 + tid;
        const int g = e / 1152;
        const int rem = e - g * 1152;
        const int tt = rem >> 7;
        const int rem2 = rem & 127;
        const int ch = rem2 >> 6;
        const int ln = rem2 & 63;
        const int o = ot * 32 + (ln & 31);
        const int cbase = g * 64 + ch * 32 + ((ln >> 5) & 1) * 16;
        int8_t bytes[16];
        #pragma unroll
        for (int b = 0; b < 16; ++b) {
            const float v = wp[((size_t)o * CC + cbase + b) * TAPS + tt];
            bytes[b] = (v > 0.f) ? (int8_t)1 : ((v < 0.f) ? (int8_t)-1 : (int8_t)0);
        }
        *(int4v*)(wpack + ((size_t)(j * 8 + ot) * 4608 + e) * 16) = *(int4v*)bytes;
    }
}

// main: i8 MFMA implicit conv. Wave shape (O=4, P=1): 4 waves = 2 o-halves x
// 2 px-tiles; each B (act) LDS fragment feeds 4 MFMAs -> B LDS traffic halved
// vs (O=2,P=2). A depth-4 / B depth-3 rings; hoisted A prologue; dbuf LDS.
__global__ __launch_bounds__(256) void conv_mfma_kernel(
    const int8_t* __restrict__ act8, const int8_t* __restrict__ wpack,
    const float* __restrict__ scales, const float* __restrict__ epack,
    const float* __restrict__ x, float* __restrict__ out)
{
    __shared__ __align__(16) int8_t lds[2][L_BUF];
    const int tid  = threadIdx.x;
    const int lane = tid & 63;
    const int wv   = __builtin_amdgcn_readfirstlane(tid >> 6);
    const int oh   = wv >> 1;            // o-half: o in [oh*128, oh*128+128)
    const int pg   = wv & 1;             // px-tile: px0 + pg*32 ..
    const int bid  = blockIdx.x;
    const int swz  = (bid & 7) * 196 + (bid >> 3);   // bijective: 1568 = 8*196
    const int pxblk = swz % 49;
    const int n     = swz / 49;
    const int px0   = pxblk * 64;
    const int h_lo  = px0 / WW;

    // per-lane swizzled LDS bases per tap col (single px-tile)
    int boff2[3];
    {
        const int p = px0 + pg * 32 + (lane & 31);
        const int hl = p / WW, wl = p % WW;
        #pragma unroll
        for (int tc = 0; tc < 3; ++tc) {
            const int col = wl + tc;
            const int a = (hl - h_lo) * L_ROW + col * L_PX + ((lane >> 5) & 1) * 16;
            boff2[tc] = a ^ SWZ(col);
        }
    }
    const size_t nbase = (size_t)n * HH;

    float fsum[4][16];
    #pragma unroll
    for (int k = 0; k < 4; ++k)
        #pragma unroll
        for (int r = 0; r < 16; ++r) fsum[k][r] = 0.f;

    int16v acc[4];
    int4v sreg[4];
    int4v Ar[4][4], Br[3];

    auto stage_load = [&](int rH, int rW, int gg) {
        #pragma unroll
        for (int k = 0; k < 4; ++k) {
            const int u = tid + k * 256;
            int4v v = {0, 0, 0, 0};
            if (u < NSTU) {
                const int r = u / 232;
                const int rem = u - r * 232;
                const int c = rem >> 2, q = rem & 3;
                const int hr = h_lo - 1 + r, wc = c - 1;
                if (hr >= 0 && hr < HH && wc >= 0 && wc < WW) {
                    int hs = hr + rH; if (hs < 0) hs += HH; else if (hs >= HH) hs -= HH;
                    int ws = wc + rW; if (ws < 0) ws += WW; else if (ws >= WW) ws -= WW;
                    v = *(const int4v*)(act8 +
                        (((nbase + hs) * WW + ws) << 8) + gg * 64 + q * 16);
                }
            }
            sreg[k] = v;
        }
    };
    auto stage_write = [&](int8_t* Ln) {
        #pragma unroll
        for (int k = 0; k < 4; ++k) {
            const int u = tid + k * 256;
            if (u < NSTU) {
                const int r = u / 232;
                const int rem = u - r * 232;
                const int c = rem >> 2, q = rem & 3;
                int a = (q >> 1) * L_CH + r * L_ROW + c * L_PX + (q & 1) * 16;
                a ^= SWZ(c);
                *(int4v*)(Ln + a) = sreg[k];
            }
        }
    };

#define LDA_P(W, S, U) do { \
        Ar[S][0] = *(const int4v*)((W) + 0 * OT_STRIDE + (U) * 1024); \
        Ar[S][1] = *(const int4v*)((W) + 1 * OT_STRIDE + (U) * 1024); \
        Ar[S][2] = *(const int4v*)((W) + 2 * OT_STRIDE + (U) * 1024); \
        Ar[S][3] = *(const int4v*)((W) + 3 * OT_STRIDE + (U) * 1024); } while (0)
#define LDB_P(S, U) do { \
        const int imm_ = ((U) & 1) * L_CH + (((U) >> 1) / 3) * L_ROW; \
        const int tc_ = ((U) >> 1) % 3; \
        Br[S] = *(const int4v*)(L + boff2[tc_] + imm_); } while (0)
#define MMX(SA, SB) do { \
        MFMA_I8(acc[0], Ar[SA][0], Br[SB]); \
        MFMA_I8(acc[1], Ar[SA][1], Br[SB]); \
        MFMA_I8(acc[2], Ar[SA][2], Br[SB]); \
        MFMA_I8(acc[3], Ar[SA][3], Br[SB]); } while (0)

    // ---- prologue: stage phase 0 (j=0 no roll, g=0); preload A units 0..3 ----
    stage_load(0, 0, 0);
    stage_write(&lds[0][0]);
    {
        const int8_t* w0b = wpack
            + ((size_t)((0 * 8 + oh * 4) * 4 + 0) * 18) * 1024 + lane * 16;
        LDA_P(w0b, 0, 0); LDA_P(w0b, 1, 1); LDA_P(w0b, 2, 2); LDA_P(w0b, 3, 3);
    }
    __syncthreads();

    #pragma unroll 1
    for (int ph = 0; ph < 12; ++ph) {
        const int j = ph >> 2, g = ph & 3;
        if ((ph & 3) == 0) {
            #pragma unroll
            for (int k = 0; k < 4; ++k)
                #pragma unroll
                for (int r = 0; r < 16; ++r) acc[k][r] = 0;
        }

        const int8_t* L = &lds[ph & 1][0];
        const int8_t* wbase = wpack
            + ((size_t)((j * 8 + oh * 4) * 4 + g) * 18) * 1024 + lane * 16;

        // B prologue (buffer valid post-barrier)
        LDB_P(0, 0); LDB_P(1, 1); LDB_P(2, 2);

        // prefetch next phase act tile into regs (GATHER roll: src[idx-amt])
        if (ph < 11) {
            const int ph2 = ph + 1;
            const int j2 = ph2 >> 2, g2 = ph2 & 3;
            const int amt2 = (j2 == 0) ? 0 : ((j2 == 1) ? 1 : 3);
            const int rH = (g2 == 0) ? -amt2 : ((g2 == 1) ? amt2 : 0);
            const int rW = (g2 == 2) ? -amt2 : ((g2 == 3) ? amt2 : 0);
            stage_load(rH, rW, g2);
        }

        __builtin_amdgcn_s_setprio(1);
        MMX(0, 0); LDA_P(wbase, 0, 4);  LDB_P(0, 3);
        MMX(1, 1); LDA_P(wbase, 1, 5);  LDB_P(1, 4);
        MMX(2, 2); LDA_P(wbase, 2, 6);  LDB_P(2, 5);
        MMX(3, 0); LDA_P(wbase, 3, 7);  LDB_P(0, 6);
        MMX(0, 1); LDA_P(wbase, 0, 8);  LDB_P(1, 7);
        MMX(1, 2); LDA_P(wbase, 1, 9);  LDB_P(2, 8);
        MMX(2, 0); LDA_P(wbase, 2, 10); LDB_P(0, 9);
        MMX(3, 1); LDA_P(wbase, 3, 11); LDB_P(1, 10);
        MMX(0, 2); LDA_P(wbase, 0, 12); LDB_P(2, 11);
        MMX(1, 0); LDA_P(wbase, 1, 13); LDB_P(0, 12);
        MMX(2, 1); LDA_P(wbase, 2, 14); LDB_P(1, 13);
        MMX(3, 2); LDA_P(wbase, 3, 15); LDB_P(2, 14);
        MMX(0, 0); LDA_P(wbase, 0, 16); LDB_P(0, 15);
        MMX(1, 1); LDA_P(wbase, 1, 17); LDB_P(1, 16);
        MMX(2, 2);                      LDB_P(2, 17);
        MMX(3, 0);
        MMX(0, 1);
        MMX(1, 2);
        __builtin_amdgcn_s_setprio(0);

        // hoisted A prologue for next phase (no LDS dependency)
        if (ph < 11) {
            const int ph2 = ph + 1;
            const int j2 = ph2 >> 2, g2 = ph2 & 3;
            const int8_t* wnext = wpack
                + ((size_t)((j2 * 8 + oh * 4) * 4 + g2) * 18) * 1024 + lane * 16;
            LDA_P(wnext, 0, 0); LDA_P(wnext, 1, 1);
            LDA_P(wnext, 2, 2); LDA_P(wnext, 3, 3);
        }

        // write next act tile into the other buffer
        if (ph < 11) stage_write(&lds[(ph + 1) & 1][0]);

        // fold at end of each j
        if ((ph & 3) == 3) {
            const float* scj = scales + j * CC + oh * 128;
            #pragma unroll
            for (int k = 0; k < 4; ++k) {
                #pragma unroll
                for (int r = 0; r < 16; ++r) {
                    const int rb = (r & 3) + 8 * (r >> 2);
                    const float slo = scj[k * 32 + rb], shi = scj[k * 32 + rb + 4];
                    const float sc = (lane & 32) ? shi : slo;
                    fsum[k][r] += sc * (float)acc[k][r];
                }
            }
        }
        __syncthreads();
    }
#undef LDA_P
#undef LDB_P
#undef MMX

    // epilogue (D layout: col=lane&31 -> px, row=(r&3)+8*(r>>2)+4*(lane>>5))
    const int voff = (lane & 31) + ((lane >> 5) & 1) * (4 * HH * WW);
    #pragma unroll
    for (int k = 0; k < 4; ++k) {
        #pragma unroll
        for (int r = 0; r < 16; ++r) {
            const int o_lo = oh * 128 + k * 32 + (r & 3) + 8 * (r >> 2);
            const float* elo = epack + o_lo * 4;
            const float* ehi = epack + (o_lo + 4) * 4;
            const bool hi = (lane & 32) != 0;
            const float e0 = hi ? ehi[0] : elo[0];
            const float e1 = hi ? ehi[1] : elo[1];
            const float e2 = hi ? ehi[2] : elo[2];
            const float e3 = hi ? ehi[3] : elo[3];
            const size_t off = ((size_t)n * CC + o_lo) * (HH * WW)
                             + px0 + pg * 32 + voff;
            float v = fsum[k][r] * e0 + e1 + x[off];
            v = (v > 0.f) ? v : e2 * v;
            out[off] = v + e3;
        }
    }
}

// ===========================================================================
extern "C" void kernel_launch(void* const* d_in, const int* in_sizes, int n_in,
                              void* d_out, int out_size, void* d_ws, size_t ws_size,
                              hipStream_t stream) {
    const float* x       = (const float*)d_in[0];
    const float* bias0   = (const float*)d_in[1];
    const float* w0      = (const float*)d_in[2];
    const float* w1      = (const float*)d_in[3];
    const float* w2      = (const float*)d_in[4];
    const float* gamma   = (const float*)d_in[5];
    const float* beta    = (const float*)d_in[6];
    const float* rmean   = (const float*)d_in[7];
    const float* rvar    = (const float*)d_in[8];
    const float* bias1   = (const float*)d_in[9];
    const float* prelu_a = (const float*)d_in[10];
    const float* bias2   = (const float*)d_in[11];
    float* out = (float*)d_out;

    int8_t* act8   = (int8_t*)d_ws;
    int8_t* wpack  = act8 + ACT8_BYTES;
    float*  scales = (float*)(wpack + WPACK_BYTES);
    float*  epack  = scales + NCONV * CC;

    pack_act8_kernel<<<dim3(BB * HH), dim3(256), 0, stream>>>(x, bias0, act8);
    pack_scales_kernel<<<dim3(NCONV * CC), dim3(64), 0, stream>>>(
        w0, w1, w2, scales, gamma, beta, rmean, rvar, bias1, prelu_a, bias2, epack);
    pack_wpack_kernel<<<dim3(NCONV * 8), dim3(256), 0, stream>>>(w0, w1, w2, wpack);
    conv_mfma_kernel<<<dim3(BB * 49), dim3(256), 0, stream>>>(
        act8, wpack, scales, epack, x, out);
}